// Round 6
// baseline (67.745 us; speedup 1.0000x reference)
//
#include <hip/hip_runtime.h>
#include <hip/hip_bf16.h>

typedef float f4 __attribute__((ext_vector_type(4)));
typedef short bf16x8 __attribute__((ext_vector_type(8)));

#define D 2048
#define RANK 16
#define NT 512

__device__ __forceinline__ short bf16_of(float x) {
    return __builtin_bit_cast(short, __float2bfloat16(x));
}

__device__ __forceinline__ bf16x8 cvt8(f4 lo, f4 hi) {
    bf16x8 r;
    r[0] = bf16_of(lo.x); r[1] = bf16_of(lo.y);
    r[2] = bf16_of(lo.z); r[3] = bf16_of(lo.w);
    r[4] = bf16_of(hi.x); r[5] = bf16_of(hi.y);
    r[6] = bf16_of(hi.z); r[7] = bf16_of(hi.w);
    return r;
}

__device__ __forceinline__ float dot4(f4 a, f4 b) {
    return a.x * b.x + a.y * b.y + a.z * b.z + a.w * b.w;
}

// LDS-write drain + raw barrier: orders ds_write->ds_read across waves but
// does NOT drain vmcnt -> global prefetch loads stay in flight across it
// (unlike __syncthreads, which the compiler fences with vmcnt(0)).
__device__ __forceinline__ void barrier_lgkm() {
    asm volatile("s_waitcnt lgkmcnt(0)" ::: "memory");
    __builtin_amdgcn_s_barrier();
}

// out = h @ (A@B)^T factored through rank-16. Two 16-row tiles per block,
// software-pipelined:
//   P1(0) -> bar -> merge(0) -> bar -> [P1(1) || P2(0)] -> bar -> merge(1)
//   -> bar -> P2(1)
// h(tile1) prefetched into registers BEFORE barrier #1 so its HBM latency
// hides under merge+P2(0). Phase1 MFMA operand map is the round-4/5
// verified one; phase2 is VALU with coalesced NT f4 stores (wave = 1KB).
__global__ __launch_bounds__(NT, 2)
void lora_pipe(const float* __restrict__ h, const float* __restrict__ A,
               const float* __restrict__ B, float* __restrict__ out) {
    const int tid  = threadIdx.x;
    const int wave = tid >> 6;
    const int lane = tid & 63;
    const int m16  = lane & 15;
    const int kg   = lane >> 4;
    const long row0 = (long)blockIdx.x * 32;

    __shared__ f4 ldsT[2][8][16][4];   // [tile][wave][row][rank-quad]
    __shared__ f4 tt[2][16][4];        // merged t, per tile

    // ---- B fragment for this wave's K-window [wave*256, wave*256+256) ----
    const float* pB = B + (long)m16 * D + wave * 256 + kg * 8;
    bf16x8 Bb[8];
#pragma unroll
    for (int s = 0; s < 8; ++s) {
        f4 b0 = *(const f4*)(pB + s * 32);
        f4 b1 = *(const f4*)(pB + s * 32 + 4);
        Bb[s] = cvt8(b0, b1);
    }

    // ---- A fragment for phase2 (issued early, reused for both tiles) ----
    f4 Af[4][4];
#pragma unroll
    for (int j = 0; j < 4; ++j)
#pragma unroll
        for (int q = 0; q < 4; ++q)
            Af[j][q] = *(const f4*)(A + (long)(tid * 4 + j) * RANK + q * 4);

    const float* ph0 = h + (row0 + m16) * D + wave * 256 + kg * 8;

    // ---- load h(tile0) ----
    f4 hc[16];
#pragma unroll
    for (int s = 0; s < 8; ++s) {
        hc[2 * s]     = *(const f4*)(ph0 + s * 32);
        hc[2 * s + 1] = *(const f4*)(ph0 + s * 32 + 4);
    }

    // ---- P1(0): two independent MFMA chains ----
    f4 a0 = {0.f, 0.f, 0.f, 0.f}, a1 = {0.f, 0.f, 0.f, 0.f};
#pragma unroll
    for (int s = 0; s < 4; ++s)
        a0 = __builtin_amdgcn_mfma_f32_16x16x32_bf16(
            Bb[s], cvt8(hc[2 * s], hc[2 * s + 1]), a0, 0, 0, 0);
#pragma unroll
    for (int s = 4; s < 8; ++s)
        a1 = __builtin_amdgcn_mfma_f32_16x16x32_bf16(
            Bb[s], cvt8(hc[2 * s], hc[2 * s + 1]), a1, 0, 0, 0);
    ldsT[0][wave][m16][kg] = a0 + a1;

    // ---- prefetch h(tile1): stays in flight across the barriers ----
    const float* ph1 = ph0 + 16 * D;
    f4 hn[16];
#pragma unroll
    for (int s = 0; s < 8; ++s) {
        hn[2 * s]     = *(const f4*)(ph1 + s * 32);
        hn[2 * s + 1] = *(const f4*)(ph1 + s * 32 + 4);
    }

    barrier_lgkm();                                    // #1: ldsT[0] ready
    if (tid < 64) {
        const int r = tid >> 2, q = tid & 3;
        f4 s = ldsT[0][0][r][q];
#pragma unroll
        for (int w = 1; w < 8; ++w) s += ldsT[0][w][r][q];
        tt[0][r][q] = s;
    }
    barrier_lgkm();                                    // #2: tt[0] ready

    // ---- P1(1) (uses prefetched hn)  ||  P2(0) (stores tile0) ----
    a0 = (f4){0.f, 0.f, 0.f, 0.f};
    a1 = (f4){0.f, 0.f, 0.f, 0.f};
#pragma unroll
    for (int s = 0; s < 4; ++s)
        a0 = __builtin_amdgcn_mfma_f32_16x16x32_bf16(
            Bb[s], cvt8(hn[2 * s], hn[2 * s + 1]), a0, 0, 0, 0);
#pragma unroll
    for (int s = 4; s < 8; ++s)
        a1 = __builtin_amdgcn_mfma_f32_16x16x32_bf16(
            Bb[s], cvt8(hn[2 * s], hn[2 * s + 1]), a1, 0, 0, 0);
    ldsT[1][wave][m16][kg] = a0 + a1;

    {
        float* po = out + row0 * D + tid * 4;
#pragma unroll
        for (int r = 0; r < 16; ++r) {
            const f4 t0 = tt[0][r][0], t1 = tt[0][r][1];
            const f4 t2 = tt[0][r][2], t3 = tt[0][r][3];
            f4 res;
            res.x = dot4(t0, Af[0][0]) + dot4(t1, Af[0][1]) +
                    dot4(t2, Af[0][2]) + dot4(t3, Af[0][3]);
            res.y = dot4(t0, Af[1][0]) + dot4(t1, Af[1][1]) +
                    dot4(t2, Af[1][2]) + dot4(t3, Af[1][3]);
            res.z = dot4(t0, Af[2][0]) + dot4(t1, Af[2][1]) +
                    dot4(t2, Af[2][2]) + dot4(t3, Af[2][3]);
            res.w = dot4(t0, Af[3][0]) + dot4(t1, Af[3][1]) +
                    dot4(t2, Af[3][2]) + dot4(t3, Af[3][3]);
            __builtin_nontemporal_store(res, (f4*)(po + (long)r * D));
        }
    }

    barrier_lgkm();                                    // #3: ldsT[1] ready
    if (tid < 64) {
        const int r = tid >> 2, q = tid & 3;
        f4 s = ldsT[1][0][r][q];
#pragma unroll
        for (int w = 1; w < 8; ++w) s += ldsT[1][w][r][q];
        tt[1][r][q] = s;
    }
    barrier_lgkm();                                    // #4: tt[1] ready

    {
        float* po = out + (row0 + 16) * D + tid * 4;
#pragma unroll
        for (int r = 0; r < 16; ++r) {
            const f4 t0 = tt[1][r][0], t1 = tt[1][r][1];
            const f4 t2 = tt[1][r][2], t3 = tt[1][r][3];
            f4 res;
            res.x = dot4(t0, Af[0][0]) + dot4(t1, Af[0][1]) +
                    dot4(t2, Af[0][2]) + dot4(t3, Af[0][3]);
            res.y = dot4(t0, Af[1][0]) + dot4(t1, Af[1][1]) +
                    dot4(t2, Af[1][2]) + dot4(t3, Af[1][3]);
            res.z = dot4(t0, Af[2][0]) + dot4(t1, Af[2][1]) +
                    dot4(t2, Af[2][2]) + dot4(t3, Af[2][3]);
            res.w = dot4(t0, Af[3][0]) + dot4(t1, Af[3][1]) +
                    dot4(t2, Af[3][2]) + dot4(t3, Af[3][3]);
            __builtin_nontemporal_store(res, (f4*)(po + (long)r * D));
        }
    }
}

extern "C" void kernel_launch(void* const* d_in, const int* in_sizes, int n_in,
                              void* d_out, int out_size, void* d_ws,
                              size_t ws_size, hipStream_t stream) {
    const float* h = (const float*)d_in[0];
    const float* A = (const float*)d_in[1];
    const float* B = (const float*)d_in[2];
    float* out = (float*)d_out;

    const int n_rows = in_sizes[0] / D;   // 16384
    const int blocks = n_rows / 32;       // 512

    hipLaunchKernelGGL(lora_pipe, dim3(blocks), dim3(NT), 0, stream,
                       h, A, B, out);
}

// Round 7
// 64.204 us; speedup vs baseline: 1.0552x; 1.0552x over previous
//
#include <hip/hip_runtime.h>
#include <hip/hip_bf16.h>

typedef float f4 __attribute__((ext_vector_type(4)));
typedef short bf16x8 __attribute__((ext_vector_type(8)));

#define D 2048
#define RANK 16
#define NT 512

__device__ __forceinline__ short bf16_of(float x) {
    return __builtin_bit_cast(short, __float2bfloat16(x));
}

__device__ __forceinline__ bf16x8 cvt8(f4 lo, f4 hi) {
    bf16x8 r;
    r[0] = bf16_of(lo.x); r[1] = bf16_of(lo.y);
    r[2] = bf16_of(lo.z); r[3] = bf16_of(lo.w);
    r[4] = bf16_of(hi.x); r[5] = bf16_of(hi.y);
    r[6] = bf16_of(hi.z); r[7] = bf16_of(hi.w);
    return r;
}

// bf16 (bit pattern in short) -> f32: single v_lshlrev
__device__ __forceinline__ float bf2f(short s) {
    return __uint_as_float(((unsigned)(unsigned short)s) << 16);
}

// LDS-drain-only barrier: global loads stay in flight across it
__device__ __forceinline__ void barrier_lgkm() {
    asm volatile("s_waitcnt lgkmcnt(0)" ::: "memory");
    __builtin_amdgcn_s_barrier();
}

// out = h @ (A@B)^T factored through rank-16.
// Phase1: per-wave MFMA T-partials over K=256 slice (verified operand map),
// LDS merge in fp32. Phase2: VALU, thread owns 4 consecutive e; the A-slice
// lives in EIGHT bf16x8 registers (8 VGPR) and is expanded with a shift in
// the row loop -- killing the 2 GB/launch L2 re-read stream that capped
// rounds 1-6 at ~60 us (round 5: VGPR=48 proved A was never resident).
__global__ __launch_bounds__(NT, 4)
void lora_v7(const float* __restrict__ h, const float* __restrict__ A,
             const float* __restrict__ B, float* __restrict__ out) {
    const int tid  = threadIdx.x;
    const int wave = tid >> 6;
    const int lane = tid & 63;
    const int m16  = lane & 15;
    const int kg   = lane >> 4;
    const long row0 = (long)blockIdx.x * 16;

    __shared__ f4 ldsT[8][16][4];   // per-wave T partials
    __shared__ f4 tt[16][4];        // merged t[row][rank-quad], fp32

    // ---- A slice as bf16: Abf[j][k] = ranks k*8..k*8+7 of e = tid*4+j ----
    bf16x8 Abf[4][2];
#pragma unroll
    for (int j = 0; j < 4; ++j) {
        const float* pa = A + (long)(tid * 4 + j) * RANK;
        f4 a0 = *(const f4*)(pa);
        f4 a1 = *(const f4*)(pa + 4);
        f4 a2 = *(const f4*)(pa + 8);
        f4 a3 = *(const f4*)(pa + 12);
        Abf[j][0] = cvt8(a0, a1);
        Abf[j][1] = cvt8(a2, a3);
    }

    // ---- B fragment for this wave's K-window [wave*256, +256) ----
    const float* pB = B + (long)m16 * D + wave * 256 + kg * 8;
    bf16x8 Bb[8];
#pragma unroll
    for (int s = 0; s < 8; ++s) {
        f4 b0 = *(const f4*)(pB + s * 32);
        f4 b1 = *(const f4*)(pB + s * 32 + 4);
        Bb[s] = cvt8(b0, b1);
    }

    // ---- phase 1: full h-tile in flight, two MFMA chains ----
    const float* ph = h + (row0 + m16) * D + wave * 256 + kg * 8;
    f4 hv[16];
#pragma unroll
    for (int s = 0; s < 8; ++s) {
        hv[2 * s]     = *(const f4*)(ph + s * 32);
        hv[2 * s + 1] = *(const f4*)(ph + s * 32 + 4);
    }
    f4 a0 = {0.f, 0.f, 0.f, 0.f}, a1 = {0.f, 0.f, 0.f, 0.f};
#pragma unroll
    for (int s = 0; s < 4; ++s)
        a0 = __builtin_amdgcn_mfma_f32_16x16x32_bf16(
            Bb[s], cvt8(hv[2 * s], hv[2 * s + 1]), a0, 0, 0, 0);
#pragma unroll
    for (int s = 4; s < 8; ++s)
        a1 = __builtin_amdgcn_mfma_f32_16x16x32_bf16(
            Bb[s], cvt8(hv[2 * s], hv[2 * s + 1]), a1, 0, 0, 0);
    ldsT[wave][m16][kg] = a0 + a1;

    barrier_lgkm();
    if (tid < 64) {
        const int r = tid >> 2, q = tid & 3;
        f4 s = ldsT[0][r][q];
#pragma unroll
        for (int w = 1; w < 8; ++w) s += ldsT[w][r][q];
        tt[r][q] = s;
    }
    barrier_lgkm();

    // ---- phase 2: 16 rows, A expanded from bf16 regs, NT f4 stores ----
    float* po = out + row0 * D + tid * 4;
#pragma unroll 4
    for (int r = 0; r < 16; ++r) {
        const f4 t0 = tt[r][0], t1 = tt[r][1];
        const f4 t2 = tt[r][2], t3 = tt[r][3];
        f4 res;
#pragma unroll
        for (int j = 0; j < 4; ++j) {
            const bf16x8 lo = Abf[j][0], hi = Abf[j][1];
            float v;
            v  = t0.x * bf2f(lo[0]) + t0.y * bf2f(lo[1]) +
                 t0.z * bf2f(lo[2]) + t0.w * bf2f(lo[3]);
            v += t1.x * bf2f(lo[4]) + t1.y * bf2f(lo[5]) +
                 t1.z * bf2f(lo[6]) + t1.w * bf2f(lo[7]);
            v += t2.x * bf2f(hi[0]) + t2.y * bf2f(hi[1]) +
                 t2.z * bf2f(hi[2]) + t2.w * bf2f(hi[3]);
            v += t3.x * bf2f(hi[4]) + t3.y * bf2f(hi[5]) +
                 t3.z * bf2f(hi[6]) + t3.w * bf2f(hi[7]);
            res[j] = v;
        }
        __builtin_nontemporal_store(res, (f4*)(po + (long)r * D));
    }
}

extern "C" void kernel_launch(void* const* d_in, const int* in_sizes, int n_in,
                              void* d_out, int out_size, void* d_ws,
                              size_t ws_size, hipStream_t stream) {
    const float* h = (const float*)d_in[0];
    const float* A = (const float*)d_in[1];
    const float* B = (const float*)d_in[2];
    float* out = (float*)d_out;

    const int n_rows = in_sizes[0] / D;   // 16384
    const int blocks = n_rows / 16;       // 1024

    hipLaunchKernelGGL(lora_v7, dim3(blocks), dim3(NT), 0, stream,
                       h, A, B, out);
}